// Round 6
// baseline (163.025 us; speedup 1.0000x reference)
//
#include <hip/hip_runtime.h>
#include <hip/hip_bf16.h>

typedef unsigned short u16;
typedef unsigned int u32;
typedef __attribute__((ext_vector_type(8))) short short8;
typedef __attribute__((ext_vector_type(4))) float f32x4;
typedef __attribute__((ext_vector_type(4))) u16 us4;
typedef __attribute__((ext_vector_type(4))) u32 u32x4;

#define MFMA16(a,b,c) __builtin_amdgcn_mfma_f32_16x16x32_bf16(a,b,c,0,0,0)

__device__ __forceinline__ u16 f2b(float x){
  u32 u = __builtin_bit_cast(u32, x);
  u32 r = (u + 0x7fffu + ((u >> 16) & 1u)) >> 16;
  return (u16)r;
}
// hardware cast (compiler pairs into v_cvt_pk_bf16_f32)
__device__ __forceinline__ u16 f2b_hw(float x){
  return __builtin_bit_cast(u16, __float2bfloat16(x));
}
__device__ __forceinline__ float ex2(float x){ return __builtin_amdgcn_exp2f(x); }

__device__ __forceinline__ void gll16(const u16* g, u16* l){
  __builtin_amdgcn_global_load_lds((const __attribute__((address_space(1))) u32*)g,
                                   (__attribute__((address_space(3))) u32*)l, 16, 0, 0);
}

// ---------------- fused f32 -> bf16 convert for Drift+Ocean ----------------
__global__ __launch_bounds__(256) void k_conv2(const float* __restrict__ a, const float* __restrict__ bsrc,
                                               u16* __restrict__ ya, u16* __restrict__ yb){
  int bid = blockIdx.x;
  const float* x = (bid < 4096) ? a : bsrc;
  u16* y = (bid < 4096) ? ya : yb;
  int i = (bid & 4095) * 256 + threadIdx.x;
  float4 v = reinterpret_cast<const float4*>(x)[i];
  us4 o; o.x = f2b(v.x); o.y = f2b(v.y); o.z = f2b(v.z); o.w = f2b(v.w);
  reinterpret_cast<us4*>(y)[i] = o;
}

// ---------------- fused weight transposes + lambda ----------------
// z=0: Wq -> WqT * (SCALE*log2e)  [exp2-domain logits]
// z=1: Wk -> WkvT rows 0..2047 ; z=2: Wv -> WkvT rows 2048..3071 ; z=3: Wo -> WoT (+ lam)
__global__ __launch_bounds__(256) void k_prep_w(const float* __restrict__ Wq, const float* __restrict__ Wk,
                                                const float* __restrict__ Wv, const float* __restrict__ Wo,
                                                u16* __restrict__ WqT, u16* __restrict__ WkvT,
                                                u16* __restrict__ WoT,
                                                const float* __restrict__ lq1, const float* __restrict__ lk1,
                                                const float* __restrict__ lq2, const float* __restrict__ lk2,
                                                float* __restrict__ lam){
  __shared__ float t[32][33];
  const int z = blockIdx.z;
  const float* W; u16* WT; int N; float scale = 1.0f;
  if (z == 0){ W = Wq; WT = WqT; N = 2048; scale = 0.1803368867f; }   // 0.125 * log2(e)
  else if (z == 1){ W = Wk; WT = WkvT; N = 2048; }
  else if (z == 2){ W = Wv; WT = WkvT + 2048*1024; N = 1024; }
  else { W = Wo; WT = WoT; N = 1024; }
  int n0 = blockIdx.x * 32, k0 = blockIdx.y * 32;
  int tx = threadIdx.x & 31, ty = threadIdx.x >> 5;
  if (n0 < N){
    #pragma unroll
    for (int i = 0; i < 4; i++)
      t[ty + i*8][tx] = W[(size_t)(k0 + ty + i*8) * N + n0 + tx];
    __syncthreads();
    #pragma unroll
    for (int i = 0; i < 4; i++)
      WT[(size_t)(n0 + ty + i*8) * 1024 + k0 + tx] = f2b(t[tx][ty + i*8] * scale);
  }
  if (z == 3 && blockIdx.x == 0 && blockIdx.y == 0 && threadIdx.x < 16){
    int h = threadIdx.x;
    float d1 = 0.f, d2 = 0.f;
    for (int i = 0; i < 64; i++){
      d1 += lq1[h*64 + i] * lk1[h*64 + i];
      d2 += lq2[h*64 + i] * lk2[h*64 + i];
    }
    lam[h] = expf(d1) - expf(d2) + 0.1f;
  }
}

// ---------------- GEMM main loop macro core ----------------
#define GEMM_MAIN_LOOP(A_, B_, m0_, n0_)                                                \
  f32x4 acc[4][4];                                                                      \
  _Pragma("unroll")                                                                     \
  for (int i = 0; i < 4; i++)                                                           \
    _Pragma("unroll")                                                                   \
    for (int j = 0; j < 4; j++){ f32x4 z = {0.f,0.f,0.f,0.f}; acc[i][j] = z; }          \
  const int srow = tid >> 3;                                                            \
  const int skc  = tid & 7;                                                             \
  for (int k0 = 0; k0 < 1024; k0 += 64){                                                \
    _Pragma("unroll")                                                                   \
    for (int c = 0; c < 4; c++){                                                        \
      int row = c*32 + srow;                                                            \
      const u16* ga = (A_) + (size_t)((m0_) + row) * 1024 + k0 + ((skc ^ (row & 7)) << 3); \
      gll16(ga, As + c*2048 + wave*512);                                                \
      const u16* gb = (B_) + (size_t)((n0_) + row) * 1024 + k0 + ((skc ^ (row & 7)) << 3); \
      gll16(gb, Bs + c*2048 + wave*512);                                                \
    }                                                                                   \
    __syncthreads();                                                                    \
    _Pragma("unroll")                                                                   \
    for (int kc = 0; kc < 2; kc++){                                                     \
      short8 af[4], bfr[4];                                                             \
      _Pragma("unroll")                                                                 \
      for (int mt = 0; mt < 4; mt++){                                                   \
        int row = wm*64 + mt*16 + lr;                                                   \
        af[mt] = *reinterpret_cast<const short8*>(As + row*64 + (((kc*4 + lg) ^ (row & 7)) << 3)); \
      }                                                                                 \
      _Pragma("unroll")                                                                 \
      for (int nt = 0; nt < 4; nt++){                                                   \
        int rown = wn*64 + nt*16 + lr;                                                  \
        bfr[nt] = *reinterpret_cast<const short8*>(Bs + rown*64 + (((kc*4 + lg) ^ (rown & 7)) << 3)); \
      }                                                                                 \
      _Pragma("unroll")                                                                 \
      for (int mt = 0; mt < 4; mt++)                                                    \
        _Pragma("unroll")                                                               \
        for (int nt = 0; nt < 4; nt++)                                                  \
          acc[mt][nt] = MFMA16(af[mt], bfr[nt], acc[mt][nt]);                           \
    }                                                                                   \
    __syncthreads();                                                                    \
  }

// standard epilogue: C[M][N] write (bf16 or f32)
template<bool OUTF32>
__device__ __forceinline__ void gemm_body(const u16* __restrict__ A, const u16* __restrict__ B,
                                          void* __restrict__ C, int N, int m0, int n0,
                                          u16* As, u16* Bs){
  const int tid = threadIdx.x;
  const int wave = tid >> 6, lane = tid & 63;
  const int lr = lane & 15, lg = lane >> 4;
  const int wm = wave >> 1, wn = wave & 1;
  GEMM_MAIN_LOOP(A, B, m0, n0)
  #pragma unroll
  for (int mt = 0; mt < 4; mt++)
    #pragma unroll
    for (int nt = 0; nt < 4; nt++)
      #pragma unroll
      for (int r = 0; r < 4; r++){
        int row = m0 + wm*64 + mt*16 + lg*4 + r;
        int col = n0 + wn*64 + nt*16 + lr;
        if (OUTF32) ((float*)C)[(size_t)row * N + col] = acc[mt][nt][r];
        else        ((u16*)C)[(size_t)row * N + col] = f2b(acc[mt][nt][r]);
      }
}

// V-projection epilogue: write VT[bh][dl][kv] directly (transposed via LDS bounce in As).
__device__ __forceinline__ void gemm_body_vt(const u16* __restrict__ A, const u16* __restrict__ B,
                                             u16* __restrict__ VT, int m0, int n0,
                                             u16* As, u16* Bs){
  const int tid = threadIdx.x;
  const int wave = tid >> 6, lane = tid & 63;
  const int lr = lane & 15, lg = lane >> 4;
  const int wm = wave >> 1, wn = wave & 1;
  GEMM_MAIN_LOOP(A, B, m0, n0)
  const int vcol0 = n0 - 2048;
  const int b = m0 >> 10;
  const int kvbase = m0 & 1023;
  // 4 chunks of 32 kv-rows bounce through As ([128 col][34-pitch row] u16)
  #pragma unroll
  for (int c = 0; c < 4; c++){
    __syncthreads();
    if (wm == (c >> 1)){
      #pragma unroll
      for (int mi = 0; mi < 2; mi++){
        int mt = (c & 1)*2 + mi;
        int rl = mi*16 + lg*4;
        #pragma unroll
        for (int nt = 0; nt < 4; nt++){
          int cl = wn*64 + nt*16 + lr;
          u32 lo = (u32)f2b(acc[mt][nt][0]) | ((u32)f2b(acc[mt][nt][1]) << 16);
          u32 hi = (u32)f2b(acc[mt][nt][2]) | ((u32)f2b(acc[mt][nt][3]) << 16);
          u32* p = (u32*)(As + cl*34 + rl);
          p[0] = lo; p[1] = hi;
        }
      }
    }
    __syncthreads();
    // coalesced read + global store: thread -> (col cl, 16-row half), 32 B each
    int cl = tid >> 1, half = tid & 1;
    const u32* src = (const u32*)(As + cl*34) + half*8;   // rows half*16 .. half*16+15
    u32x4 w0, w1;
    w0.x = src[0]; w0.y = src[1]; w0.z = src[2]; w0.w = src[3];
    w1.x = src[4]; w1.y = src[5]; w1.z = src[6]; w1.w = src[7];
    int vcol = vcol0 + cl;
    int hh = vcol >> 6, dl = vcol & 63;
    u16* dst = VT + (size_t)(b*16 + hh)*65536 + (size_t)dl*1024 + kvbase + c*32 + half*16;
    *reinterpret_cast<u32x4*>(dst) = w0;
    *reinterpret_cast<u32x4*>(dst + 8) = w1;
  }
}

// fused projection GEMM:
//  bid<512  : Q  = Xd*WqT^T  [4096][2048]
//  n-tile<16: KV K-region [4096][cols 0..2047]
//  n-tile>=16: V rows -> written TRANSPOSED straight to VT [64 bh][64 d][1024 kv]
__global__ __launch_bounds__(256) void k_gemm_proj(const u16* __restrict__ Xd, const u16* __restrict__ Xo,
                                                   const u16* __restrict__ WqT, const u16* __restrict__ WkvT,
                                                   u16* __restrict__ Qb, u16* __restrict__ KVb,
                                                   u16* __restrict__ VT){
  __shared__ __align__(16) u16 As[128*64];
  __shared__ __align__(16) u16 Bs[128*64];
  int bid = blockIdx.x;
  if (bid < 512){
    gemm_body<false>(Xd, WqT, Qb, 2048, (bid >> 4) * 128, (bid & 15) * 128, As, Bs);
  } else {
    int t = bid - 512;
    int mt8 = t / 24, nt8 = t % 24;
    if (nt8 < 16)
      gemm_body<false>(Xo, WkvT, KVb, 3072, mt8 * 128, nt8 * 128, As, Bs);
    else
      gemm_body_vt(Xo, WkvT, VT, mt8 * 128, nt8 * 128, As, Bs);
  }
}

// output GEMM: out = Ob * WoT^T, f32 out
__global__ __launch_bounds__(256) void k_gemm_out(const u16* __restrict__ A, const u16* __restrict__ B,
                                                  float* __restrict__ C){
  __shared__ __align__(16) u16 As[128*64];
  __shared__ __align__(16) u16 Bs[128*64];
  int bid = blockIdx.x;
  gemm_body<true>(A, B, C, 1024, (bid >> 3) * 128, (bid & 7) * 128, As, Bs);
}

// ---------------- in-lane online softmax on S^T, exp2 domain (lane q = lr) ----------------
__device__ __forceinline__ void softmax_t(f32x4 s[4], float& m, float& l, f32x4 (&ob)[4][2], int qt,
                                          u16* pl, int lr, int lg){
  float a0 = fmaxf(fmaxf(s[0][0], s[0][1]), fmaxf(s[0][2], s[0][3]));
  float a1 = fmaxf(fmaxf(s[1][0], s[1][1]), fmaxf(s[1][2], s[1][3]));
  float a2 = fmaxf(fmaxf(s[2][0], s[2][1]), fmaxf(s[2][2], s[2][3]));
  float a3 = fmaxf(fmaxf(s[3][0], s[3][1]), fmaxf(s[3][2], s[3][3]));
  float mx = fmaxf(fmaxf(a0, a1), fmaxf(a2, a3));
  mx = fmaxf(mx, __shfl_xor(mx, 16));
  mx = fmaxf(mx, __shfl_xor(mx, 32));
  if (__any(mx > m + 11.54f)){                     // 8 ln-units in log2 domain
    float nm = fmaxf(m, mx);
    float al = ex2(m - nm);
    m = nm; l *= al;
    #pragma unroll
    for (int nt = 0; nt < 4; nt++)
      #pragma unroll
      for (int r = 0; r < 4; r++) ob[nt][qt][r] *= al;
  }
  float sum = 0.f;
  #pragma unroll
  for (int nt = 0; nt < 4; nt++)
    #pragma unroll
    for (int r = 0; r < 4; r++){
      float p = ex2(s[nt][r] - m);
      s[nt][r] = p;
      sum += p;
    }
  sum += __shfl_xor(sum, 16);
  sum += __shfl_xor(sum, 32);
  l += sum;
  char* base = (char*)pl + lr * 128;
  const int swz = (lr & 7) << 4;
  #pragma unroll
  for (int nt = 0; nt < 4; nt++){
    us4 h;
    h.x = f2b_hw(s[nt][0]); h.y = f2b_hw(s[nt][1]);
    h.z = f2b_hw(s[nt][2]); h.w = f2b_hw(s[nt][3]);
    *reinterpret_cast<us4*>(base + ((nt*32 + lg*8) ^ swz)) = h;
  }
}

// ---------------- differential flash attention: LDS-staged K/V, 128q/block ----------------
__global__ __launch_bounds__(256, 2) void k_attn(const u16* __restrict__ Q, const u16* __restrict__ KVb,
                                                 const u16* __restrict__ VT, const float* __restrict__ lam,
                                                 u16* __restrict__ O){
  int bid = blockIdx.x;
  int logical = (bid & 7) * 64 + (bid >> 3);           // 512 % 8 == 0, bijective
  int qt8 = logical & 7, h = (logical >> 3) & 15, b = logical >> 7;
  const int tid = threadIdx.x, wave = tid >> 6, lane = tid & 63;
  const int lr = lane & 15, lg = lane >> 4;
  const int qb = qt8 * 128 + wave * 32;

  __shared__ __align__(16) u16 Ks[2][8192];            // [buf][64 kv][128 d] chunk-swizzled
  __shared__ __align__(16) u16 Vs[2][4096];            // [buf][64 d][64 kv] chunk-swizzled
  __shared__ __align__(16) u16 Pl[4][2][2][1024];      // [wave][qt][branch][16 q][64 kv]

  const int srow = tid >> 4, schunk = tid & 15;
  const int vrow = tid >> 3, vchunk = tid & 7;
  const u16* Kg = KVb + (size_t)(b*1024 + srow) * 3072 + h*128 + ((schunk ^ (srow & 7)) << 3);
  const u16* Vg = VT + (size_t)(b*16 + h) * 65536 + (size_t)vrow * 1024 + ((vchunk ^ (vrow & 7)) << 3);

  short8 qf[2][2][2];                                  // [branch][qt][kc]
  #pragma unroll
  for (int qt = 0; qt < 2; qt++){
    const u16* Qp = Q + (size_t)(b*1024 + qb + qt*16 + lr) * 2048 + h*128 + lg*8;
    #pragma unroll
    for (int kc = 0; kc < 2; kc++){
      qf[0][qt][kc] = *reinterpret_cast<const short8*>(Qp + kc*32);
      qf[1][qt][kc] = *reinterpret_cast<const short8*>(Qp + 64 + kc*32);
    }
  }
  const float lamh = lam[h];

  f32x4 o[2][4][2];
  #pragma unroll
  for (int br = 0; br < 2; br++)
    #pragma unroll
    for (int nt = 0; nt < 4; nt++)
      #pragma unroll
      for (int qt = 0; qt < 2; qt++){ f32x4 z = {0.f,0.f,0.f,0.f}; o[br][nt][qt] = z; }
  float m[2][2], l[2][2];
  #pragma unroll
  for (int br = 0; br < 2; br++)
    #pragma unroll
    for (int qt = 0; qt < 2; qt++){ m[br][qt] = -3.0e38f; l[br][qt] = 0.f; }

  auto STAGE = [&](int buf, int kv0){
    u16* kd = &Ks[buf][tid * 8];
    #pragma unroll
    for (int i = 0; i < 4; i++)
      gll16(Kg + (size_t)(kv0 + i*16) * 3072, kd + i*2048);
    u16* vd = &Vs[buf][tid * 8];
    #pragma unroll
    for (int j = 0; j < 2; j++)
      gll16(Vg + kv0 + (size_t)(j*32) * 1024, vd + j*2048);
  };

  STAGE(0, 0);
  __syncthreads();

  for (int t = 0; t < 16; t++){
    const int cur = t & 1;
    if (t < 15) STAGE(cur ^ 1, (t + 1) << 6);

    const u16* kbuf = &Ks[cur][0];
    const u16* vbuf = &Vs[cur][0];

    #pragma unroll
    for (int br = 0; br < 2; br++){
      short8 kf[4][2];
      #pragma unroll
      for (int nt = 0; nt < 4; nt++)
        #pragma unroll
        for (int kc = 0; kc < 2; kc++)
          kf[nt][kc] = *reinterpret_cast<const short8*>(
              kbuf + (nt*16 + lr)*128 + (((br*8 + kc*4 + lg) ^ (lr & 7)) << 3));
      #pragma unroll
      for (int qt = 0; qt < 2; qt++){
        f32x4 s[4];
        #pragma unroll
        for (int nt = 0; nt < 4; nt++){ f32x4 z = {0.f,0.f,0.f,0.f}; s[nt] = z; }
        __builtin_amdgcn_s_setprio(1);
        #pragma unroll
        for (int nt = 0; nt < 4; nt++)
          #pragma unroll
          for (int kc = 0; kc < 2; kc++)
            s[nt] = MFMA16(kf[nt][kc], qf[br][qt][kc], s[nt]);
        __builtin_amdgcn_s_setprio(0);
        softmax_t(s, m[br][qt], l[br][qt], o[br], qt, &Pl[wave][qt][br][0], lr, lg);
      }
    }

    const int swz = (lr & 7) << 4;
    __builtin_amdgcn_s_setprio(1);
    #pragma unroll
    for (int kc = 0; kc < 2; kc++){
      short8 pf[2][2];
      #pragma unroll
      for (int qt = 0; qt < 2; qt++)
        #pragma unroll
        for (int br = 0; br < 2; br++)
          pf[qt][br] = *reinterpret_cast<const short8*>(
              (char*)&Pl[wave][qt][br][0] + lr*128 + ((kc*64 + lg*16) ^ swz));
      #pragma unroll
      for (int nt = 0; nt < 4; nt++){
        short8 vf = *reinterpret_cast<const short8*>(
            vbuf + (nt*16 + lr)*64 + (((kc*4 + lg) ^ (lr & 7)) << 3));
        #pragma unroll
        for (int qt = 0; qt < 2; qt++){
          o[0][nt][qt] = MFMA16(vf, pf[qt][0], o[0][nt][qt]);
          o[1][nt][qt] = MFMA16(vf, pf[qt][1], o[1][nt][qt]);
        }
      }
    }
    __builtin_amdgcn_s_setprio(0);
    __syncthreads();
  }

  #pragma unroll
  for (int qt = 0; qt < 2; qt++){
    const float inv1 = 1.0f / l[0][qt];
    const float inv2 = lamh / l[1][qt];
    u16* Op = O + (size_t)(b*1024 + qb + qt*16 + lr) * 1024 + h*64;
    #pragma unroll
    for (int nt = 0; nt < 4; nt++){
      us4 hh;
      #pragma unroll
      for (int r = 0; r < 4; r++){
        float v = o[0][nt][qt][r] * inv1 - o[1][nt][qt][r] * inv2;
        ((u16*)&hh)[r] = f2b_hw(v);
      }
      *reinterpret_cast<us4*>(Op + nt*16 + lg*4) = hh;
    }
  }
}

// ---------------- launch ----------------
extern "C" void kernel_launch(void* const* d_in, const int* in_sizes, int n_in,
                              void* d_out, int out_size, void* d_ws, size_t ws_size,
                              hipStream_t stream){
  const float* Drift = (const float*)d_in[0];
  const float* Ocean = (const float*)d_in[1];
  const float* Wq    = (const float*)d_in[2];
  const float* Wk    = (const float*)d_in[3];
  const float* Wv    = (const float*)d_in[4];
  const float* Wo    = (const float*)d_in[5];
  const float* lq1   = (const float*)d_in[6];
  const float* lk1   = (const float*)d_in[7];
  const float* lq2   = (const float*)d_in[8];
  const float* lk2   = (const float*)d_in[9];
  float* out = (float*)d_out;

  char* ws = (char*)d_ws;
  u16* Xd   = (u16*)(ws);                      // 4096x1024 bf16
  u16* Xo   = (u16*)(ws + 8388608);            // 4096x1024
  u16* WqT  = (u16*)(ws + 16777216);           // 2048x1024
  u16* WkvT = (u16*)(ws + 20971520);           // 3072x1024
  u16* WoT  = (u16*)(ws + 27262976);           // 1024x1024
  u16* Qb   = (u16*)(ws + 29360128);           // 4096x2048
  u16* KVb  = (u16*)(ws + 46137344);           // 4096x3072 (V region unused)
  u16* VTb  = (u16*)(ws + 71303168);           // 64x64x1024
  u16* Ob   = (u16*)(ws + 79691776);           // 4096x1024
  float* lam = (float*)(ws + 88080384);        // 16 f32

  k_conv2<<<8192, 256, 0, stream>>>(Drift, Ocean, Xd, Xo);
  k_prep_w<<<dim3(64,32,4), 256, 0, stream>>>(Wq, Wk, Wv, Wo, WqT, WkvT, WoT,
                                              lq1, lk1, lq2, lk2, lam);
  k_gemm_proj<<<1280, 256, 0, stream>>>(Xd, Xo, WqT, WkvT, Qb, KVb, VTb);
  k_attn<<<512, 256, 0, stream>>>(Qb, KVb, VTb, lam, Ob);
  k_gemm_out<<<256, 256, 0, stream>>>(Ob, WoT, out);
}